// Round 6
// baseline (214.746 us; speedup 1.0000x reference)
//
#include <hip/hip_runtime.h>
#include <math.h>

#define N1C 50176
#define N2C 12544
#define N3C 3136
#define NT_TILES (N2C * 8 / 64)   // 1568 conv tiles (64 cols each)

typedef __attribute__((ext_vector_type(8))) short bf16x8;
typedef __attribute__((ext_vector_type(4))) float f32x4;

__device__ __forceinline__ unsigned short f2bf(float f) {
    unsigned u = __builtin_bit_cast(unsigned, f);
    u += 0x7fffu + ((u >> 16) & 1u);
    return (unsigned short)(u >> 16);
}
__device__ __forceinline__ unsigned packbf(float a, float b) {
    return (unsigned)f2bf(a) | ((unsigned)f2bf(b) << 16);
}
// single-instruction RNE pack of 2 f32 -> 2 bf16 (no builtin on gfx950; T12 recipe)
__device__ __forceinline__ unsigned cvtpk(float lo, float hi) {
    unsigned r;
    asm("v_cvt_pk_bf16_f32 %0, %1, %2" : "=v"(r) : "v"(lo), "v"(hi));
    return r;
}
__device__ __forceinline__ float bf2f(unsigned short u) {
    return __builtin_bit_cast(float, (unsigned)u << 16);
}
__device__ __forceinline__ float bflo(unsigned u) {
    return __builtin_bit_cast(float, u << 16);
}
__device__ __forceinline__ float bfhi(unsigned u) {
    return __builtin_bit_cast(float, u & 0xffff0000u);
}

// ---------------- fused prologue: transpose | mlp(off1+off2) | pad_w(W1,W2,W3) ----------------
#define TRB (N1C / 64)            // 784
#define MLB (2 * N2C * 9 / 256)   // 882  (first 441 -> A1, rest -> A2; boundary block-aligned)
#define PWB 112                   // (1024+9216+18432)/256

__device__ __forceinline__ void pad_one(int i, const float* __restrict__ W,
                                        unsigned short* __restrict__ Wp,
                                        int OC, int CIN, int KT) {
    int j = i & 7;
    int op = (i >> 3) & 31;
    int q = (i >> 8) & 3;
    int kt = (i >> 10) % KT;
    int g = i / (KT * 1024);
    int kp = kt * 32 + q * 8 + j;
    int t = kp / CIN, c = kp - t * CIN;
    int o = g * 32 + op;
    float v = (t < 9 && o < OC) ? W[(o * CIN + c) * 9 + t] : 0.f;
    Wp[i] = f2bf(v);
}

__global__ void prologue_kernel(const float* __restrict__ x, unsigned short* __restrict__ X0,
                                const float* __restrict__ off1, const float* __restrict__ off2,
                                const float* __restrict__ Wh, const float* __restrict__ bh,
                                const float* __restrict__ Wo, const float* __restrict__ bo,
                                float* __restrict__ A1, float* __restrict__ A2,
                                const float* __restrict__ W1, const float* __restrict__ W2,
                                const float* __restrict__ W3,
                                unsigned short* __restrict__ W1p, unsigned short* __restrict__ W2p,
                                unsigned short* __restrict__ W3p) {
    __shared__ float U[2304];     // transpose tile (1600 used) | A staging (2304)
    int blk = blockIdx.x;
    int tid = threadIdx.x;
    if (blk < TRB) {
        int n0 = blk * 64;
        for (int r = tid; r < 24 * 64; r += 256) {
            int cb = r >> 6;
            int nn = r & 63;
            U[nn * 25 + cb] = x[cb * N1C + n0 + nn];
        }
        __syncthreads();
        for (int w = tid; w < 64 * 24; w += 256) {
            int nn = w / 24;
            int u = w - nn * 24;
            X0[(n0 + nn) * 24 + u] = f2bf(U[nn * 25 + u]);
        }
    } else if (blk < TRB + MLB) {
        int bi = blk - TRB;
        int idx = bi * 256 + tid;
        const float* offp;
        if (idx < N2C * 9) offp = off1 + idx * 2;
        else offp = off2 + (idx - N2C * 9) * 2;
        float o0 = offp[0], o1 = offp[1];
        float out[9];
#pragma unroll
        for (int t = 0; t < 9; t++) out[t] = bo[t];
#pragma unroll
        for (int h = 0; h < 32; h++) {
            float hv = fmaxf(o0 * Wh[h] + o1 * Wh[32 + h] + bh[h], 0.f);
#pragma unroll
            for (int t = 0; t < 9; t++) out[t] += hv * Wo[h * 9 + t];
        }
#pragma unroll
        for (int t = 0; t < 9; t++) U[tid * 9 + t] = out[t];   // stride 9: conflict-free
        __syncthreads();
        float* dst = (bi < 441) ? (A1 + (size_t)bi * 2304)
                                : (A2 + (size_t)(bi - 441) * 2304);
        for (int i = tid; i < 2304; i += 256) dst[i] = U[i];   // coalesced
    } else {
        int i = (blk - TRB - MLB) * 256 + tid;
        if (i < 1024) pad_one(i, W1, W1p, 32, 3, 1);
        else if (i < 10240) pad_one(i - 1024, W2, W2p, 32, 32, 9);
        else pad_one(i - 10240, W3, W3p, 64, 32, 9);
    }
}

// ---------------- conv1: CIN=3 gather+weight -> LDS S -> MFMA (single tile/block) ----------------
template <int CIN, int MW, bool HAS_BN>   // instantiated with CIN=3 only
__global__ __launch_bounds__(256, 4)
void conv_kernel(const unsigned short* __restrict__ Xin,
                 const int* __restrict__ nbr,
                 const float* __restrict__ A,
                 const unsigned short* __restrict__ Wp,
                 const float* __restrict__ bias,
                 const float* __restrict__ bnsc,
                 const float* __restrict__ bnsh,
                 unsigned short* __restrict__ Yb,
                 double* __restrict__ Part) {
    constexpr int OC = MW * 16;
    constexpr int KREAL = 9 * CIN;
    constexpr int KROW = (KREAL + 31) & ~31;
    constexpr int KT = KROW / 32;
    constexpr int KSTR = KROW + 8;
    constexpr int PARTS = 256 / OC;
    constexpr int PCOLS = 64 / PARTS;
    constexpr int OSH = (OC == 32) ? 5 : 6;
    constexpr int YSTR = OC + 4;
    constexpr int SB1 = 64 * KSTR * 2;
    constexpr int SB2 = 64 * YSTR * 4 + PARTS * 2 * OC * 4;
    constexpr int SBYTES = SB1 > SB2 ? SB1 : SB2;
    __shared__ alignas(16) char Sraw[SBYTES];
    __shared__ float a_lds[8 * 81];
    short* S = (short*)Sraw;

    int tid = threadIdx.x;
    int tile = blockIdx.x;
    int n0 = tile * 8;

    for (int i = tid; i < 64 * KSTR; i += 256) S[i] = 0;   // zero pad slots
    for (int i = tid; i < 648; i += 256) a_lds[i] = A[(size_t)n0 * 81 + i];
    __syncthreads();
    if (tid < 192) {
        int nsub = tid / 24;
        int u = tid - nsub * 24;          // u = b*3+c
        int b = u / 3, c = u - b * 3;
        int n = n0 + nsub;
        const int* nb = nbr + n * 9;
        const float* Ar = a_lds + nsub * 81;
        float s[9];
#pragma unroll
        for (int t = 0; t < 9; t++) s[t] = 0.f;
#pragma unroll
        for (int k = 0; k < 9; k++) {
            float f = bf2f(Xin[nb[k] * 24 + u]);
#pragma unroll
            for (int t = 0; t < 9; t++) s[t] = fmaf(Ar[k * 9 + t], f, s[t]);
        }
        int col = nsub * 8 + b;
#pragma unroll
        for (int t = 0; t < 9; t++) S[col * KSTR + t * 3 + c] = (short)f2bf(s[t]);
    }
    __syncthreads();

    int lane = tid & 63, wv = tid >> 6, q = lane >> 4, cl = lane & 15;
    int colg = wv * 16 + cl;

    const bf16x8* wf = (const bf16x8*)Wp;
    f32x4 acc[MW];
#pragma unroll
    for (int m = 0; m < MW; m++) acc[m] = (f32x4){0.f, 0.f, 0.f, 0.f};
#pragma unroll
    for (int kt = 0; kt < KT; kt++) {
        bf16x8 bfr = *(const bf16x8*)&S[colg * KSTR + kt * 32 + q * 8];
#pragma unroll
        for (int m = 0; m < MW; m++) {
            const bf16x8* wg = wf + (m >> 1) * (KT * 128);
            bf16x8 am = wg[(kt * 4 + q) * 32 + cl + (m & 1) * 16];
            acc[m] = __builtin_amdgcn_mfma_f32_16x16x32_bf16(am, bfr, acc[m], 0, 0, 0);
        }
    }
    __syncthreads();

    float* Yf = (float*)Sraw;
    float* P2f = Yf + 64 * YSTR;
    int C = tile * 64 + colg;
#pragma unroll
    for (int m = 0; m < MW; m++) {
        f32x4 v;
#pragma unroll
        for (int i = 0; i < 4; i++) v[i] = acc[m][i] + bias[m * 16 + q * 4 + i];
        *(f32x4*)&Yf[colg * YSTR + m * 16 + q * 4] = v;
        uint2 pk;
        pk.x = cvtpk(v[0], v[1]);
        pk.y = cvtpk(v[2], v[3]);
        *(uint2*)&Yb[(size_t)C * OC + m * 16 + q * 4] = pk;
    }
    __syncthreads();
    {
        int o = tid & (OC - 1);
        int part = tid >> OSH;
        float s = 0.f, qq = 0.f;
#pragma unroll
        for (int i = 0; i < PCOLS; i++) {
            float y = Yf[(part * PCOLS + i) * YSTR + o];
            s += y;
            qq += y * y;
        }
        P2f[part * 2 * OC + o] = s;
        P2f[part * 2 * OC + OC + o] = qq;
    }
    __syncthreads();
    if (tid < 2 * OC) {
        double v = 0.0;
#pragma unroll
        for (int p = 0; p < PARTS; p++) v += (double)P2f[p * 2 * OC + tid];
        Part[(size_t)tid * NT_TILES + tile] = v;
    }
}

// ---------------- conv32: 2 tiles/block, half-tile gather pipelining, cvt_pk ----------------
// Xin bf16 [col][c] (col=n*8+b); Yb bf16 [col][OC]; Part[2*OC][NT_TILES] (double, transposed)
template <int MW>   // MW = OC/16; BN always on
__global__ __launch_bounds__(256, 4)
void conv32_kernel(const unsigned short* __restrict__ Xin,
                   const int* __restrict__ nbr,
                   const float* __restrict__ A,
                   const unsigned short* __restrict__ Wp,
                   const float* __restrict__ bias,
                   const float* __restrict__ bnsc,
                   const float* __restrict__ bnsh,
                   unsigned short* __restrict__ Yb,
                   double* __restrict__ Part) {
    constexpr int OC = MW * 16;
    constexpr int KROW = 288;
    constexpr int KT = 9;
    constexpr int KSTR = KROW + 8;            // 296
    constexpr int PARTS = 256 / OC;           // 8 / 4
    constexpr int PCOLS = 64 / PARTS;         // 8 / 16
    constexpr int OSH = (OC == 32) ? 5 : 6;
    constexpr int YSTR = OC + 4;
    constexpr int SB1 = 64 * KSTR * 2;        // 37888
    constexpr int SB2 = 64 * YSTR * 4 + PARTS * 2 * OC * 4;
    constexpr int SBYTES = SB1 > SB2 ? SB1 : SB2;
    __shared__ alignas(16) char Sraw[SBYTES];
    __shared__ float a_lds[8 * 81];
    short* S = (short*)Sraw;

    int tid = threadIdx.x;
    int tile0 = blockIdx.x * 2;

    int wv4 = __builtin_amdgcn_readfirstlane(tid >> 6);   // wave id (uniform)
    int lane = tid & 63;
    int b = lane >> 3, c4 = lane & 7;
    float4 scv = *(const float4*)&bnsc[4 * c4];
    float4 shv = *(const float4*)&bnsh[4 * c4];
    const uint2* Xd = (const uint2*)Xin;      // node row = 64 uint2 (512B)

    // issue 9 gathers for (tile, half gg) into fu[9] — wave-uniform nbr (s_load base)
    auto issue_half = [&](int tile, int gg, uint2* fu) {
        int nb = (tile * 8 + wv4 * 2 + gg) * 9;
#pragma unroll
        for (int k = 0; k < 9; k++) {
            int j = nbr[nb + k];
            fu[k] = Xd[(size_t)j * 64 + lane];
        }
    };
    auto stage_a = [&](int tile) {
        for (int i = tid; i < 648; i += 256) a_lds[i] = A[(size_t)tile * 648 + i];
    };
    auto compute_half = [&](int gg, const uint2* fu) {
        const float* Ar = a_lds + (wv4 * 2 + gg) * 81;
        float s0[9], s1[9], s2[9], s3[9];
#pragma unroll
        for (int t = 0; t < 9; t++) { s0[t] = 0.f; s1[t] = 0.f; s2[t] = 0.f; s3[t] = 0.f; }
#pragma unroll
        for (int k = 0; k < 9; k++) {
            uint2 u = fu[k];
            float f0 = fmaxf(fmaf(bflo(u.x), scv.x, shv.x), 0.f);
            float f1 = fmaxf(fmaf(bfhi(u.x), scv.y, shv.y), 0.f);
            float f2 = fmaxf(fmaf(bflo(u.y), scv.z, shv.z), 0.f);
            float f3 = fmaxf(fmaf(bfhi(u.y), scv.w, shv.w), 0.f);
#pragma unroll
            for (int t = 0; t < 9; t++) {
                float a = Ar[k * 9 + t];
                s0[t] = fmaf(a, f0, s0[t]);
                s1[t] = fmaf(a, f1, s1[t]);
                s2[t] = fmaf(a, f2, s2[t]);
                s3[t] = fmaf(a, f3, s3[t]);
            }
        }
        int col = (wv4 * 2 + gg) * 8 + b;
        uint2* Srow = (uint2*)&S[col * KSTR];
#pragma unroll
        for (int t = 0; t < 9; t++) {
            uint2 pk;
            pk.x = cvtpk(s0[t], s1[t]);
            pk.y = cvtpk(s2[t], s3[t]);
            Srow[t * 8 + c4] = pk;              // short off = t*32 + 4*c4
        }
    };

    int wv = tid >> 6, q = lane >> 4, cl = lane & 15;
    int colg = wv * 16 + cl;
    const bf16x8* wf = (const bf16x8*)Wp;
    float* Yf = (float*)Sraw;
    float* P2f = Yf + 64 * YSTR;

    uint2 fuA[9], fuB[9];
    issue_half(tile0, 0, fuA);
    stage_a(tile0);
    __syncthreads();                          // a_lds(t0) ready

#pragma unroll 1
    for (int it = 0; it < 2; ++it) {
        int tile = tile0 + it;
        issue_half(tile, 1, fuB);             // 2nd half flies under 1st-half compute
        compute_half(0, fuA);
        compute_half(1, fuB);
        __syncthreads();                      // S ready
        if (it == 0) issue_half(tile0 + 1, 0, fuA);   // next tile's 1st half under MFMA+epi

        f32x4 acc[MW];
#pragma unroll
        for (int m = 0; m < MW; m++) acc[m] = (f32x4){0.f, 0.f, 0.f, 0.f};
#pragma unroll
        for (int kt = 0; kt < KT; kt++) {
            bf16x8 bfr = *(const bf16x8*)&S[colg * KSTR + kt * 32 + q * 8];
#pragma unroll
            for (int m = 0; m < MW; m++) {
                const bf16x8* wg = wf + (m >> 1) * (KT * 128);
                bf16x8 am = wg[(kt * 4 + q) * 32 + cl + (m & 1) * 16];
                acc[m] = __builtin_amdgcn_mfma_f32_16x16x32_bf16(am, bfr, acc[m], 0, 0, 0);
            }
        }
        __syncthreads();                      // S reads done -> Sraw reusable as scratch

        int C = tile * 64 + colg;
#pragma unroll
        for (int m = 0; m < MW; m++) {
            f32x4 v;
#pragma unroll
            for (int i = 0; i < 4; i++) v[i] = acc[m][i] + bias[m * 16 + q * 4 + i];
            *(f32x4*)&Yf[colg * YSTR + m * 16 + q * 4] = v;
            uint2 pk;
            pk.x = cvtpk(v[0], v[1]);
            pk.y = cvtpk(v[2], v[3]);
            *(uint2*)&Yb[(size_t)C * OC + m * 16 + q * 4] = pk;
        }
        if (it == 0) stage_a(tile0 + 1);      // a_lds reads all done pre-MFMA-sync
        __syncthreads();
        {
            int o = tid & (OC - 1);
            int part = tid >> OSH;
            float s = 0.f, qq = 0.f;
#pragma unroll
            for (int i = 0; i < PCOLS; i++) {
                float y = Yf[(part * PCOLS + i) * YSTR + o];
                s += y;
                qq += y * y;
            }
            P2f[part * 2 * OC + o] = s;
            P2f[part * 2 * OC + OC + o] = qq;
        }
        __syncthreads();
        if (tid < 2 * OC) {
            double v = 0.0;
#pragma unroll
            for (int p = 0; p < PARTS; p++) v += (double)P2f[p * 2 * OC + tid];
            Part[(size_t)tid * NT_TILES + tile] = v;
        }
        if (it == 0) __syncthreads();         // protect Yf/P2f before next tile's S writes
    }
}

// ---------------- BN reduce+finalize: one block per channel ----------------
__global__ __launch_bounds__(256, 8)
void bn_reduce(const double* __restrict__ Part,
               const float* __restrict__ g, const float* __restrict__ be,
               float* __restrict__ sc, float* __restrict__ sh, int OC) {
    int o = blockIdx.x;
    int tid = threadIdx.x;
    const double* ps = Part + (size_t)o * NT_TILES;
    const double* pq = Part + (size_t)(OC + o) * NT_TILES;
    double s = 0.0, q = 0.0;
    for (int t = tid; t < NT_TILES; t += 256) {
        s += ps[t];
        q += pq[t];
    }
#pragma unroll
    for (int d = 1; d < 64; d <<= 1) {
        s += __shfl_xor(s, d);
        q += __shfl_xor(q, d);
    }
    __shared__ double red[8];
    int wv = tid >> 6;
    if ((tid & 63) == 0) { red[wv] = s; red[4 + wv] = q; }
    __syncthreads();
    if (tid == 0) {
        double S = red[0] + red[1] + red[2] + red[3];
        double Q = red[4] + red[5] + red[6] + red[7];
        double cnt = (double)N2C * 8.0;
        double mean = S / cnt;
        double var = Q / cnt - mean * mean;
        double rs = 1.0 / sqrt(var + 1e-5);
        double scale = (double)g[o] * rs;
        sc[o] = (float)scale;
        sh[o] = (float)((double)be[o] - mean * scale);
    }
}

// ---------------- pool: 2 m per 256-thr block; thread owns a channel pair ----------------
__global__ __launch_bounds__(256, 8)
void pool_kernel(const unsigned short* __restrict__ Y3, const int* __restrict__ pidx,
                 const float* __restrict__ sc, const float* __restrict__ sh,
                 float* __restrict__ out) {
    int m0 = blockIdx.x * 2;
    int tid = threadIdx.x;      // b*32 + o2  (o2 = channel pair)
    int o2 = tid & 31;
    int b = tid >> 5;
    float s0 = sc[2 * o2], h0 = sh[2 * o2];
    float s1 = sc[2 * o2 + 1], h1 = sh[2 * o2 + 1];
    const unsigned* Y3u = (const unsigned*)Y3;
    int j0[9], j1[9];
#pragma unroll
    for (int k = 0; k < 9; k++) {
        j0[k] = pidx[m0 * 9 + k];
        j1[k] = pidx[m0 * 9 + 9 + k];
    }
    unsigned u0[9], u1[9];                      // all 18 gathers in flight
#pragma unroll
    for (int k = 0; k < 9; k++) u0[k] = Y3u[(size_t)j0[k] * 256 + tid];
#pragma unroll
    for (int k = 0; k < 9; k++) u1[k] = Y3u[(size_t)j1[k] * 256 + tid];
    float a0 = 0.f, a1 = 0.f, c0 = 0.f, c1 = 0.f;
#pragma unroll
    for (int k = 0; k < 9; k++) {
        a0 = fmaxf(a0, fmaf(bflo(u0[k]), s0, h0));
        a1 = fmaxf(a1, fmaf(bfhi(u0[k]), s1, h1));
        c0 = fmaxf(c0, fmaf(bflo(u1[k]), s0, h0));
        c1 = fmaxf(c1, fmaf(bfhi(u1[k]), s1, h1));
    }
    float2 r0 = {a0, c0};       // channel 2*o2,   m0 / m0+1
    float2 r1 = {a1, c1};       // channel 2*o2+1, m0 / m0+1
    *(float2*)(out + (size_t)(b * 64 + 2 * o2) * 3136 + m0) = r0;
    *(float2*)(out + (size_t)(b * 64 + 2 * o2 + 1) * 3136 + m0) = r1;
}

extern "C" void kernel_launch(void* const* d_in, const int* in_sizes, int n_in,
                              void* d_out, int out_size, void* d_ws, size_t ws_size,
                              hipStream_t stream) {
    const float* x    = (const float*)d_in[0];
    const int*   nbr1 = (const int*)d_in[1];
    const float* off1 = (const float*)d_in[2];
    const int*   nbr2 = (const int*)d_in[3];
    const float* off2 = (const float*)d_in[4];
    const int*   pidx = (const int*)d_in[5];
    const float* Wh   = (const float*)d_in[6];
    const float* bh   = (const float*)d_in[7];
    const float* Wo   = (const float*)d_in[8];
    const float* bo   = (const float*)d_in[9];
    const float* W1   = (const float*)d_in[10];
    const float* b1   = (const float*)d_in[11];
    const float* W2   = (const float*)d_in[12];
    const float* b2   = (const float*)d_in[13];
    const float* W3   = (const float*)d_in[14];
    const float* b3   = (const float*)d_in[15];
    const float* g1   = (const float*)d_in[16];
    const float* be1  = (const float*)d_in[17];
    const float* g2   = (const float*)d_in[18];
    const float* be2  = (const float*)d_in[19];
    const float* g3   = (const float*)d_in[20];
    const float* be3  = (const float*)d_in[21];

    char* ws = (char*)d_ws;
    size_t off = 0;
    auto alloc = [&](size_t bytes) -> void* {
        void* p = ws + off;
        off += (bytes + 255) & ~(size_t)255;
        return p;
    };
    unsigned short* X0b = (unsigned short*)alloc((size_t)N1C * 24 * 2);   // 2.4MB
    float* A1 = (float*)alloc((size_t)N2C * 81 * 4);                      // 4.1MB
    float* A2 = (float*)alloc((size_t)N2C * 81 * 4);                      // 4.1MB
    unsigned short* Y1b = (unsigned short*)alloc((size_t)N2C * 8 * 32 * 2);  // 6.4MB
    unsigned short* Y2b = (unsigned short*)alloc((size_t)N2C * 8 * 32 * 2);  // 6.4MB
    unsigned short* Y3b = (unsigned short*)alloc((size_t)N2C * 8 * 64 * 2);  // 12.8MB
    unsigned short* W1p = (unsigned short*)alloc(32 * 32 * 2);
    unsigned short* W2p = (unsigned short*)alloc(32 * 288 * 2);
    unsigned short* W3p = (unsigned short*)alloc(64 * 288 * 2);
    double* Part  = (double*)alloc((size_t)NT_TILES * 128 * 8);           // 1.6MB
    float*  scbuf = (float*)alloc(256 * 4);

    float* sc1 = scbuf;       float* sh1 = scbuf + 32;
    float* sc2 = scbuf + 64;  float* sh2 = scbuf + 96;
    float* sc3 = scbuf + 128; float* sh3 = scbuf + 192;

    prologue_kernel<<<TRB + MLB + PWB, 256, 0, stream>>>(
        x, X0b, off1, off2, Wh, bh, Wo, bo, A1, A2, W1, W2, W3, W1p, W2p, W3p);

    conv_kernel<3, 2, false><<<NT_TILES, 256, 0, stream>>>(
        X0b, nbr1, A1, W1p, b1, nullptr, nullptr, Y1b, Part);
    bn_reduce<<<32, 256, 0, stream>>>(Part, g1, be1, sc1, sh1, 32);

    conv32_kernel<2><<<NT_TILES / 2, 256, 0, stream>>>(
        Y1b, nbr2, A2, W2p, b2, sc1, sh1, Y2b, Part);
    bn_reduce<<<32, 256, 0, stream>>>(Part, g2, be2, sc2, sh2, 32);

    conv32_kernel<4><<<NT_TILES / 2, 256, 0, stream>>>(
        Y2b, nbr2, A2, W3p, b3, sc2, sh2, Y3b, Part);
    bn_reduce<<<64, 256, 0, stream>>>(Part, g3, be3, sc3, sh3, 64);

    pool_kernel<<<N3C / 2, 256, 0, stream>>>(Y3b, pidx, sc3, sh3, (float*)d_out);
}

// Round 7
// 187.584 us; speedup vs baseline: 1.1448x; 1.1448x over previous
//
#include <hip/hip_runtime.h>
#include <math.h>

#define N1C 50176
#define N2C 12544
#define N3C 3136
#define NT_TILES (N2C * 8 / 64)   // 1568 conv tiles (64 cols each)

typedef __attribute__((ext_vector_type(8))) short bf16x8;
typedef __attribute__((ext_vector_type(4))) float f32x4;

__device__ __forceinline__ unsigned short f2bf(float f) {
    unsigned u = __builtin_bit_cast(unsigned, f);
    u += 0x7fffu + ((u >> 16) & 1u);
    return (unsigned short)(u >> 16);
}
// single-instruction RNE pack of 2 f32 -> 2 bf16
__device__ __forceinline__ unsigned cvtpk(float lo, float hi) {
    unsigned r;
    asm("v_cvt_pk_bf16_f32 %0, %1, %2" : "=v"(r) : "v"(lo), "v"(hi));
    return r;
}
__device__ __forceinline__ float bf2f(unsigned short u) {
    return __builtin_bit_cast(float, (unsigned)u << 16);
}
__device__ __forceinline__ float bflo(unsigned u) {
    return __builtin_bit_cast(float, u << 16);
}
__device__ __forceinline__ float bfhi(unsigned u) {
    return __builtin_bit_cast(float, u & 0xffff0000u);
}

// ---------------- fused prologue: transpose | mlp(off1+off2) | pad_w(W1,W2,W3) ----------------
#define TRB (N1C / 64)            // 784
#define MLB (2 * N2C * 9 / 256)   // 882  (first 441 -> A1, rest -> A2; boundary block-aligned)
#define PWB 112                   // (1024+9216+18432)/256

__device__ __forceinline__ void pad_one(int i, const float* __restrict__ W,
                                        unsigned short* __restrict__ Wp,
                                        int OC, int CIN, int KT) {
    int j = i & 7;
    int op = (i >> 3) & 31;
    int q = (i >> 8) & 3;
    int kt = (i >> 10) % KT;
    int g = i / (KT * 1024);
    int kp = kt * 32 + q * 8 + j;
    int t = kp / CIN, c = kp - t * CIN;
    int o = g * 32 + op;
    float v = (t < 9 && o < OC) ? W[(o * CIN + c) * 9 + t] : 0.f;
    Wp[i] = f2bf(v);
}

__global__ void prologue_kernel(const float* __restrict__ x, unsigned short* __restrict__ X0,
                                const float* __restrict__ off1, const float* __restrict__ off2,
                                const float* __restrict__ Wh, const float* __restrict__ bh,
                                const float* __restrict__ Wo, const float* __restrict__ bo,
                                float* __restrict__ A1, float* __restrict__ A2,
                                const float* __restrict__ W1, const float* __restrict__ W2,
                                const float* __restrict__ W3,
                                unsigned short* __restrict__ W1p, unsigned short* __restrict__ W2p,
                                unsigned short* __restrict__ W3p) {
    __shared__ float U[2304];     // transpose tile (1600 used) | A staging (2304)
    int blk = blockIdx.x;
    int tid = threadIdx.x;
    if (blk < TRB) {
        int n0 = blk * 64;
        for (int r = tid; r < 24 * 64; r += 256) {
            int cb = r >> 6;
            int nn = r & 63;
            U[nn * 25 + cb] = x[cb * N1C + n0 + nn];
        }
        __syncthreads();
        for (int w = tid; w < 64 * 24; w += 256) {
            int nn = w / 24;
            int u = w - nn * 24;
            X0[(n0 + nn) * 24 + u] = f2bf(U[nn * 25 + u]);
        }
    } else if (blk < TRB + MLB) {
        int bi = blk - TRB;
        int idx = bi * 256 + tid;
        const float* offp;
        if (idx < N2C * 9) offp = off1 + idx * 2;
        else offp = off2 + (idx - N2C * 9) * 2;
        float o0 = offp[0], o1 = offp[1];
        float out[9];
#pragma unroll
        for (int t = 0; t < 9; t++) out[t] = bo[t];
#pragma unroll
        for (int h = 0; h < 32; h++) {
            float hv = fmaxf(o0 * Wh[h] + o1 * Wh[32 + h] + bh[h], 0.f);
#pragma unroll
            for (int t = 0; t < 9; t++) out[t] += hv * Wo[h * 9 + t];
        }
#pragma unroll
        for (int t = 0; t < 9; t++) U[tid * 9 + t] = out[t];   // stride 9: conflict-free
        __syncthreads();
        float* dst = (bi < 441) ? (A1 + (size_t)bi * 2304)
                                : (A2 + (size_t)(bi - 441) * 2304);
        for (int i = tid; i < 2304; i += 256) dst[i] = U[i];   // coalesced
    } else {
        int i = (blk - TRB - MLB) * 256 + tid;
        if (i < 1024) pad_one(i, W1, W1p, 32, 3, 1);
        else if (i < 10240) pad_one(i - 1024, W2, W2p, 32, 32, 9);
        else pad_one(i - 10240, W3, W3p, 64, 32, 9);
    }
}

// ---------------- fused interp-conv: gather+weight -> LDS S -> MFMA ----------------
// Xin bf16: CIN=3: [n][b*3+c]; CIN=32: [col][c] (col=n*8+b)
// Yb bf16:  [col][OC];  Part[2*OC][NT_TILES] BN partials (double, transposed)
// 1 tile/block: fu[18] live only in phase A (no spills; round-6 lesson: cross-tile
// register pipelining exceeds the 128-VGPR cap and spills ~100MB to scratch)
template <int CIN, int MW, bool HAS_BN>   // MW = OC/16
__global__ __launch_bounds__(256, 4)
void conv_kernel(const unsigned short* __restrict__ Xin,
                 const int* __restrict__ nbr,
                 const float* __restrict__ A,
                 const unsigned short* __restrict__ Wp,   // fragment-major bf16
                 const float* __restrict__ bias,
                 const float* __restrict__ bnsc,
                 const float* __restrict__ bnsh,
                 unsigned short* __restrict__ Yb,
                 double* __restrict__ Part) {
    constexpr int OC = MW * 16;
    constexpr int KREAL = 9 * CIN;
    constexpr int KROW = (KREAL + 31) & ~31;  // 32 / 288
    constexpr int KT = KROW / 32;
    constexpr int KSTR = KROW + 8;            // 40 / 296 (uint2-safe)
    constexpr int PARTS = 256 / OC;           // 8 / 4
    constexpr int PCOLS = 64 / PARTS;         // 8 / 16
    constexpr int OSH = (OC == 32) ? 5 : 6;
    constexpr int YSTR = OC + 4;              // f32 scratch stride (dword%32=4 -> conflict-free)
    constexpr int SB1 = 64 * KSTR * 2;
    constexpr int SB2 = 64 * YSTR * 4 + PARTS * 2 * OC * 4;
    constexpr int SBYTES = SB1 > SB2 ? SB1 : SB2;
    __shared__ alignas(16) char Sraw[SBYTES];
    __shared__ float a_lds[8 * 81];           // interp weights for this block's 8 nodes
    short* S = (short*)Sraw;

    int tid = threadIdx.x;
    int tile = blockIdx.x;
    int n0 = tile * 8;

    // ---- phase A: S[col][t*CIN+c] = sum_k a[n,k,t] * bnrelu(feat) ----
    if constexpr (CIN == 3) {
        for (int i = tid; i < 64 * KSTR; i += 256) S[i] = 0;   // zero pad slots
        for (int i = tid; i < 648; i += 256) a_lds[i] = A[(size_t)n0 * 81 + i];
        __syncthreads();
        if (tid < 192) {
            int nsub = tid / 24;
            int u = tid - nsub * 24;          // u = b*3+c
            int b = u / 3, c = u - b * 3;
            int n = n0 + nsub;
            const int* nb = nbr + n * 9;
            const float* Ar = a_lds + nsub * 81;
            float s[9];
#pragma unroll
            for (int t = 0; t < 9; t++) s[t] = 0.f;
#pragma unroll
            for (int k = 0; k < 9; k++) {
                float f = bf2f(Xin[nb[k] * 24 + u]);
#pragma unroll
                for (int t = 0; t < 9; t++) s[t] = fmaf(Ar[k * 9 + t], f, s[t]);
            }
            int col = nsub * 8 + b;
#pragma unroll
            for (int t = 0; t < 9; t++) S[col * KSTR + t * 3 + c] = (short)f2bf(s[t]);
        }
    } else {
        // wave wv owns nodes {2wv, 2wv+1}; lane = b*8 + c4 (c4 = 4-channel group)
        int wv4 = __builtin_amdgcn_readfirstlane(tid >> 6);
        int lane = tid & 63;
        int b = lane >> 3, c4 = lane & 7;
        float4 scv = {1.f, 1.f, 1.f, 1.f}, shv = {0.f, 0.f, 0.f, 0.f};
        if (HAS_BN) {
            scv = *(const float4*)&bnsc[4 * c4];
            shv = *(const float4*)&bnsh[4 * c4];
        }
        const uint2* Xd = (const uint2*)Xin;   // node row = 64 uint2 (512B)
        uint2 fu[18];                          // all 18 gathers issued upfront
#pragma unroll
        for (int gg = 0; gg < 2; gg++)
#pragma unroll
            for (int k = 0; k < 9; k++) {
                int j = nbr[(n0 + wv4 * 2 + gg) * 9 + k];   // wave-uniform -> s_load
                fu[gg * 9 + k] = Xd[(size_t)j * 64 + lane];
            }
        // stage A rows to LDS while gathers fly (no SGPR pressure, broadcast reads)
        for (int i = tid; i < 648; i += 256) a_lds[i] = A[(size_t)n0 * 81 + i];
        __syncthreads();
#pragma unroll
        for (int gg = 0; gg < 2; gg++) {
            const float* Ar = a_lds + (wv4 * 2 + gg) * 81;
            float s0[9], s1[9], s2[9], s3[9];
#pragma unroll
            for (int t = 0; t < 9; t++) { s0[t] = 0.f; s1[t] = 0.f; s2[t] = 0.f; s3[t] = 0.f; }
#pragma unroll
            for (int k = 0; k < 9; k++) {
                uint2 u = fu[gg * 9 + k];
                float f0 = bflo(u.x), f1 = bfhi(u.x);
                float f2 = bflo(u.y), f3 = bfhi(u.y);
                if (HAS_BN) {
                    f0 = fmaxf(fmaf(f0, scv.x, shv.x), 0.f);
                    f1 = fmaxf(fmaf(f1, scv.y, shv.y), 0.f);
                    f2 = fmaxf(fmaf(f2, scv.z, shv.z), 0.f);
                    f3 = fmaxf(fmaf(f3, scv.w, shv.w), 0.f);
                }
#pragma unroll
                for (int t = 0; t < 9; t++) {
                    float a = Ar[k * 9 + t];
                    s0[t] = fmaf(a, f0, s0[t]);
                    s1[t] = fmaf(a, f1, s1[t]);
                    s2[t] = fmaf(a, f2, s2[t]);
                    s3[t] = fmaf(a, f3, s3[t]);
                }
            }
            int col = (wv4 * 2 + gg) * 8 + b;
            uint2* Srow = (uint2*)&S[col * KSTR];
#pragma unroll
            for (int t = 0; t < 9; t++) {
                uint2 pk;
                pk.x = cvtpk(s0[t], s1[t]);
                pk.y = cvtpk(s2[t], s3[t]);
                Srow[t * 8 + c4] = pk;              // short off = t*32 + 4*c4
            }
        }
    }
    __syncthreads();

    // ---- phase B: MFMA, W frags straight from global (L2-hot) ----
    int lane = tid & 63, wv = tid >> 6, q = lane >> 4, cl = lane & 15;
    int colg = wv * 16 + cl;

    const bf16x8* wf = (const bf16x8*)Wp;
    f32x4 acc[MW];
#pragma unroll
    for (int m = 0; m < MW; m++) acc[m] = (f32x4){0.f, 0.f, 0.f, 0.f};
#pragma unroll
    for (int kt = 0; kt < KT; kt++) {
        bf16x8 bfr = *(const bf16x8*)&S[colg * KSTR + kt * 32 + q * 8];
#pragma unroll
        for (int m = 0; m < MW; m++) {
            const bf16x8* wg = wf + (m >> 1) * (KT * 128);
            bf16x8 am = wg[(kt * 4 + q) * 32 + cl + (m & 1) * 16];
            acc[m] = __builtin_amdgcn_mfma_f32_16x16x32_bf16(am, bfr, acc[m], 0, 0, 0);
        }
    }
    __syncthreads();            // S reads done -> reuse LDS as f32 scratch

    float* Yf = (float*)Sraw;             // [64][YSTR]
    float* P2f = Yf + 64 * YSTR;          // [PARTS][2*OC]
    int C = tile * 64 + colg;             // global col = n*8+b
#pragma unroll
    for (int m = 0; m < MW; m++) {
        f32x4 v;
#pragma unroll
        for (int i = 0; i < 4; i++) v[i] = acc[m][i] + bias[m * 16 + q * 4 + i];
        *(f32x4*)&Yf[colg * YSTR + m * 16 + q * 4] = v;     // ds_write_b128
        uint2 pk;
        pk.x = cvtpk(v[0], v[1]);
        pk.y = cvtpk(v[2], v[3]);
        *(uint2*)&Yb[(size_t)C * OC + m * 16 + q * 4] = pk; // 8B global store
    }
    __syncthreads();
    {
        int o = tid & (OC - 1);
        int part = tid >> OSH;
        float s = 0.f, qq = 0.f;
#pragma unroll
        for (int i = 0; i < PCOLS; i++) {
            float y = Yf[(part * PCOLS + i) * YSTR + o];     // wave reads rows: conflict-free
            s += y;
            qq += y * y;
        }
        P2f[part * 2 * OC + o] = s;
        P2f[part * 2 * OC + OC + o] = qq;
    }
    __syncthreads();
    if (tid < 2 * OC) {
        double v = 0.0;
#pragma unroll
        for (int p = 0; p < PARTS; p++) v += (double)P2f[p * 2 * OC + tid];
        Part[(size_t)tid * NT_TILES + tile] = v;   // transposed: coalesced in bn_reduce
    }
}

// ---------------- BN reduce+finalize: one block per channel ----------------
__global__ __launch_bounds__(256, 8)
void bn_reduce(const double* __restrict__ Part,
               const float* __restrict__ g, const float* __restrict__ be,
               float* __restrict__ sc, float* __restrict__ sh, int OC) {
    int o = blockIdx.x;
    int tid = threadIdx.x;
    const double* ps = Part + (size_t)o * NT_TILES;
    const double* pq = Part + (size_t)(OC + o) * NT_TILES;
    double s = 0.0, q = 0.0;
    for (int t = tid; t < NT_TILES; t += 256) {
        s += ps[t];
        q += pq[t];
    }
#pragma unroll
    for (int d = 1; d < 64; d <<= 1) {
        s += __shfl_xor(s, d);
        q += __shfl_xor(q, d);
    }
    __shared__ double red[8];
    int wv = tid >> 6;
    if ((tid & 63) == 0) { red[wv] = s; red[4 + wv] = q; }
    __syncthreads();
    if (tid == 0) {
        double S = red[0] + red[1] + red[2] + red[3];
        double Q = red[4] + red[5] + red[6] + red[7];
        double cnt = (double)N2C * 8.0;
        double mean = S / cnt;
        double var = Q / cnt - mean * mean;
        double rs = 1.0 / sqrt(var + 1e-5);
        double scale = (double)g[o] * rs;
        sc[o] = (float)scale;
        sh[o] = (float)((double)be[o] - mean * scale);
    }
}

// ---------------- pool: 2 m per 256-thr block; thread owns a channel pair ----------------
__global__ __launch_bounds__(256, 8)
void pool_kernel(const unsigned short* __restrict__ Y3, const int* __restrict__ pidx,
                 const float* __restrict__ sc, const float* __restrict__ sh,
                 float* __restrict__ out) {
    int m0 = blockIdx.x * 2;
    int tid = threadIdx.x;      // b*32 + o2  (o2 = channel pair)
    int o2 = tid & 31;
    int b = tid >> 5;
    float s0 = sc[2 * o2], h0 = sh[2 * o2];
    float s1 = sc[2 * o2 + 1], h1 = sh[2 * o2 + 1];
    const unsigned* Y3u = (const unsigned*)Y3;
    int j0[9], j1[9];
#pragma unroll
    for (int k = 0; k < 9; k++) {
        j0[k] = pidx[m0 * 9 + k];
        j1[k] = pidx[m0 * 9 + 9 + k];
    }
    unsigned u0[9], u1[9];                      // all 18 gathers in flight
#pragma unroll
    for (int k = 0; k < 9; k++) u0[k] = Y3u[(size_t)j0[k] * 256 + tid];
#pragma unroll
    for (int k = 0; k < 9; k++) u1[k] = Y3u[(size_t)j1[k] * 256 + tid];
    float a0 = 0.f, a1 = 0.f, c0 = 0.f, c1 = 0.f;
#pragma unroll
    for (int k = 0; k < 9; k++) {
        a0 = fmaxf(a0, fmaf(bflo(u0[k]), s0, h0));
        a1 = fmaxf(a1, fmaf(bfhi(u0[k]), s1, h1));
        c0 = fmaxf(c0, fmaf(bflo(u1[k]), s0, h0));
        c1 = fmaxf(c1, fmaf(bfhi(u1[k]), s1, h1));
    }
    float2 r0 = {a0, c0};       // channel 2*o2,   m0 / m0+1
    float2 r1 = {a1, c1};       // channel 2*o2+1, m0 / m0+1
    *(float2*)(out + (size_t)(b * 64 + 2 * o2) * 3136 + m0) = r0;
    *(float2*)(out + (size_t)(b * 64 + 2 * o2 + 1) * 3136 + m0) = r1;
}

extern "C" void kernel_launch(void* const* d_in, const int* in_sizes, int n_in,
                              void* d_out, int out_size, void* d_ws, size_t ws_size,
                              hipStream_t stream) {
    const float* x    = (const float*)d_in[0];
    const int*   nbr1 = (const int*)d_in[1];
    const float* off1 = (const float*)d_in[2];
    const int*   nbr2 = (const int*)d_in[3];
    const float* off2 = (const float*)d_in[4];
    const int*   pidx = (const int*)d_in[5];
    const float* Wh   = (const float*)d_in[6];
    const float* bh   = (const float*)d_in[7];
    const float* Wo   = (const float*)d_in[8];
    const float* bo   = (const float*)d_in[9];
    const float* W1   = (const float*)d_in[10];
    const float* b1   = (const float*)d_in[11];
    const float* W2   = (const float*)d_in[12];
    const float* b2   = (const float*)d_in[13];
    const float* W3   = (const float*)d_in[14];
    const float* b3   = (const float*)d_in[15];
    const float* g1   = (const float*)d_in[16];
    const float* be1  = (const float*)d_in[17];
    const float* g2   = (const float*)d_in[18];
    const float* be2  = (const float*)d_in[19];
    const float* g3   = (const float*)d_in[20];
    const float* be3  = (const float*)d_in[21];

    char* ws = (char*)d_ws;
    size_t off = 0;
    auto alloc = [&](size_t bytes) -> void* {
        void* p = ws + off;
        off += (bytes + 255) & ~(size_t)255;
        return p;
    };
    unsigned short* X0b = (unsigned short*)alloc((size_t)N1C * 24 * 2);   // 2.4MB
    float* A1 = (float*)alloc((size_t)N2C * 81 * 4);                      // 4.1MB
    float* A2 = (float*)alloc((size_t)N2C * 81 * 4);                      // 4.1MB
    unsigned short* Y1b = (unsigned short*)alloc((size_t)N2C * 8 * 32 * 2);  // 6.4MB
    unsigned short* Y2b = (unsigned short*)alloc((size_t)N2C * 8 * 32 * 2);  // 6.4MB
    unsigned short* Y3b = (unsigned short*)alloc((size_t)N2C * 8 * 64 * 2);  // 12.8MB
    unsigned short* W1p = (unsigned short*)alloc(32 * 32 * 2);
    unsigned short* W2p = (unsigned short*)alloc(32 * 288 * 2);
    unsigned short* W3p = (unsigned short*)alloc(64 * 288 * 2);
    double* Part  = (double*)alloc((size_t)NT_TILES * 128 * 8);           // 1.6MB
    float*  scbuf = (float*)alloc(256 * 4);

    float* sc1 = scbuf;       float* sh1 = scbuf + 32;
    float* sc2 = scbuf + 64;  float* sh2 = scbuf + 96;
    float* sc3 = scbuf + 128; float* sh3 = scbuf + 192;

    prologue_kernel<<<TRB + MLB + PWB, 256, 0, stream>>>(
        x, X0b, off1, off2, Wh, bh, Wo, bo, A1, A2, W1, W2, W3, W1p, W2p, W3p);

    conv_kernel<3, 2, false><<<NT_TILES, 256, 0, stream>>>(
        X0b, nbr1, A1, W1p, b1, nullptr, nullptr, Y1b, Part);
    bn_reduce<<<32, 256, 0, stream>>>(Part, g1, be1, sc1, sh1, 32);

    conv_kernel<32, 2, true><<<NT_TILES, 256, 0, stream>>>(
        Y1b, nbr2, A2, W2p, b2, sc1, sh1, Y2b, Part);
    bn_reduce<<<32, 256, 0, stream>>>(Part, g2, be2, sc2, sh2, 32);

    conv_kernel<32, 4, true><<<NT_TILES, 256, 0, stream>>>(
        Y2b, nbr2, A2, W3p, b3, sc2, sh2, Y3b, Part);
    bn_reduce<<<64, 256, 0, stream>>>(Part, g3, be3, sc3, sh3, 64);

    pool_kernel<<<N3C / 2, 256, 0, stream>>>(Y3b, pidx, sc3, sh3, (float*)d_out);
}